// Round 9
// baseline (415.560 us; speedup 1.0000x reference)
//
#include <hip/hip_runtime.h>

#define CN 16
#define HN 128
#define IMH 256
#define IMW 256
#define HW (IMH * IMW)

typedef __attribute__((ext_vector_type(8))) short short8;
typedef __attribute__((ext_vector_type(4))) float float4v;
typedef __attribute__((ext_vector_type(2))) unsigned int uint2v;
typedef __attribute__((ext_vector_type(4))) unsigned int uint4v;

__device__ __forceinline__ unsigned int f2bf(float f) {
    unsigned int u = __builtin_bit_cast(unsigned int, f);
    u += 0x7FFFu + ((u >> 16) & 1u);          // round-to-nearest-even
    return u >> 16;
}
// HW packed f32->bf16 (RNE, identical rounding to f2bf): 1 VALU op instead of ~10
__device__ __forceinline__ unsigned int pack2(float a, float b) {
    unsigned int r;
    asm("v_cvt_pk_bf16_f32 %0, %1, %2" : "=v"(r) : "v"(a), "v"(b));
    return r;
}

// ybuf swizzle key: must spread banks on BOTH store (r fixed, qd varies) and
// read (row = 16nt+l15) sides. p&7 was 16-way-conflicted on the quad store (R8).
__device__ __forceinline__ int ykey(int p) {
    return (((p & 3) << 1) ^ (p >> 2)) & 7;
}

// ---------------- Weight prep: fragment-ordered bf16 weights ----------------
// Physical k-slot permutation (must match nca_mfma's ybuf pack):
//   slot s = 32ks + 8q + j; cp = s>>3 = 4ks+q; m = s&7 = j.
//   m<6  -> w1[hid][6*cp + m]   (features of channel pair cp: {cen,sx,sy}x2)
//   s==6 -> b1[hid]             (bias; y slot 6 = 1.0 from the cp==0 pack word)
//   else -> 0                   (slots 8cp+6,7: y is garbage/zero, weight 0)
__global__ void nca_prep(const float* __restrict__ w1, const float* __restrict__ b1,
                         const float* __restrict__ w2,
                         unsigned short* __restrict__ a1f, unsigned short* __restrict__ b2f)
{
    int t = blockIdx.x * 256 + threadIdx.x;
    if (t < 8192) {
        int j = t & 7, lane = (t >> 3) & 63, ks = (t >> 9) & 1, mi = t >> 10;
        int hid = 16 * mi + (lane & 15);
        int cp = 4 * ks + (lane >> 4);
        float v = 0.f;
        if (j < 6) v = w1[hid * 48 + 6 * cp + j];
        else if (cp == 0 && j == 6) v = b1[hid];
        a1f[t] = (unsigned short)f2bf(v);
    }
    if (t < 2048) {
        int j = t & 7, lane = (t >> 3) & 63, ks = t >> 9;
        b2f[t] = (unsigned short)f2bf(w2[(lane & 15) * HN + 32 * ks + 8 * (lane >> 4) + j]);
    }
}

// ---------------- Kernel A: perception + MFMA MLP + update ----------------
// 128 pixels/block (4x32), 256 threads = 4 waves.
// LDS = 16384 (sx/hb union) + 16384 (ybuf) + 8192 (xcT) = 40960 B -> 4 blocks/CU.
// Session rules: grid 8x64x32 IS the L2 blocking scheme (R3). launch_bounds(256,4)
// only — (256,5) forces VGPR 48 + spills (R4). Nothing extra lives in VGPRs across
// perception (R5). Wave-slot occupancy is not the limiter (R6). xcT in LDS beats
// global x re-read by ~9us (R6/R7). Store wave-pairing does NOT merge HBM write
// sectors (R8: WRITE flat) — write excess is a granularity floor, don't chase.
// R9: ybuf swizzle key (((p&3)<<1)^(p>>2))&7 — R8's p&7 key collapsed the quad
// store into 2 bank groups (16-way, SQ_LDS_BANK_CONFLICT 6.8M->16.35M).
__global__ __launch_bounds__(256, 4) void nca_mfma(
    const float* __restrict__ x, const float* __restrict__ upd,
    const unsigned short* __restrict__ a1f, const unsigned short* __restrict__ b2f,
    float* __restrict__ out, float* __restrict__ xn3, unsigned char* __restrict__ bm)
{
    __shared__ __align__(16) union {
        float sx[6][16][36];               // 13824 B (staging; pitch 36 -> rows 16B-aligned)
        unsigned short hb[4][16][128];     // 16384 B (per-wave h scratch, swizzled)
    } u;
    __shared__ __align__(16) unsigned short ybuf[128][64];   // 16384 B (ykey-swizzled, pitch 128B)
    __shared__ __align__(16) float xcT[16][128];             //  8192 B (x centers, XOR-swizzled)

    const int b   = blockIdx.z;
    const int i0  = blockIdx.y * 4;
    const int j0  = blockIdx.x * 32;
    const int tid = threadIdx.x;
    const int lane = tid & 63, w = tid >> 6;
    const int l15 = lane & 15, q = lane >> 4;
    const float* xb = x + (size_t)b * CN * HW;
    const float* ub = upd + (size_t)b * HW;

    // ---- weight fragment loads (L1/L2-hot; compiler sinks to use site) ----
    short8 a1[8][2];
#pragma unroll
    for (int mi = 0; mi < 8; ++mi)
#pragma unroll
        for (int ks = 0; ks < 2; ++ks)
            a1[mi][ks] = *(const short8*)(a1f + ((mi * 2 + ks) * 64 + lane) * 8);
    short8 b2[4];
#pragma unroll
    for (int ks = 0; ks < 4; ++ks)
        b2[ks] = *(const short8*)(b2f + (ks * 64 + lane) * 8);

    // ---- stage x tile (+1 halo): sx[row 0..5][ch][col 0..33]; cols 34,35 unused ----
    const bool interior = (blockIdx.y > 0) & (blockIdx.y < 63) & (blockIdx.x > 0) & (blockIdx.x < 7);
    {
        const int col = tid & 31;
        if (interior) {
            const float* src = xb + (i0 - 1) * IMW + (j0 - 1);
#pragma unroll
            for (int rt = tid >> 5; rt < 96; rt += 8)
                u.sx[rt >> 4][rt & 15][col] = src[(rt & 15) * HW + (rt >> 4) * IMW + col];
            if (tid < 192) {
                int rt = tid >> 1, col2 = 32 + (tid & 1);
                u.sx[rt >> 4][rt & 15][col2] = src[(rt & 15) * HW + (rt >> 4) * IMW + col2];
            }
        } else {
#pragma unroll
            for (int rt = tid >> 5; rt < 96; rt += 8) {
                int rr = rt >> 4, c = rt & 15;
                int gi = i0 + rr - 1, gj = j0 + col - 1;
                float v = 0.f;
                if ((unsigned)gi < IMH && (unsigned)gj < IMW) v = xb[c * HW + gi * IMW + gj];
                u.sx[rr][c][col] = v;
            }
            if (tid < 192) {
                int rt = tid >> 1, col2 = 32 + (tid & 1);
                int rr = rt >> 4, c = rt & 15;
                int gi = i0 + rr - 1, gj = j0 + col2 - 1;
                float v = 0.f;
                if ((unsigned)gi < IMH && (unsigned)gj < IMW) v = xb[c * HW + gi * IMW + gj];
                u.sx[rr][c][col2] = v;
            }
        }
    }
    __syncthreads();

    // ---- perception: thread = (pixel-quad qd, channel-pair cp) ----
    // Pixel p = 4*qd + r (r=0..3). sx col for global col j0+t is t+1; quad reads
    // aligned cols tx4..tx4+7 covering pixels tx4-1..tx4+6 -> pixel r uses f[r..r+2].
    const int qd  = tid & 31;
    const int cp  = tid >> 5;              // wave-uniform pairs {2w,2w+1}
    const int ty  = qd >> 3, tx4 = (qd & 7) << 2;

    unsigned int w0p[4], w1p[4], w2p[4];
    float4v cen0v, cen1v;
    {   // channel c0 = 2cp
        const int c = 2 * cp;
        float4v r0a = *(const float4v*)&u.sx[ty][c][tx4];
        float4v r0b = *(const float4v*)&u.sx[ty][c][tx4 + 4];
        float4v r1a = *(const float4v*)&u.sx[ty + 1][c][tx4];
        float4v r1b = *(const float4v*)&u.sx[ty + 1][c][tx4 + 4];
        float4v r2a = *(const float4v*)&u.sx[ty + 2][c][tx4];
        float4v r2b = *(const float4v*)&u.sx[ty + 2][c][tx4 + 4];
        float S[6], D[6];
#pragma unroll
        for (int j = 0; j < 6; ++j) {
            float a0 = (j < 4) ? r0a[j] : r0b[j - 4];
            float a1v = (j < 4) ? r1a[j] : r1b[j - 4];
            float a2 = (j < 4) ? r2a[j] : r2b[j - 4];
            S[j] = fmaf(2.f, a1v, a0) + a2;
            D[j] = a2 - a0;
        }
        float sy0[4];
#pragma unroll
        for (int r = 0; r < 4; ++r) {
            float cen = (r + 1 < 4) ? r1a[r + 1] : r1b[r - 3];
            float sxv = (S[r + 2] - S[r]) * 0.125f;
            sy0[r] = (fmaf(2.f, D[r + 1], D[r]) + D[r + 2]) * 0.125f;
            w0p[r] = pack2(cen, sxv);
            cen0v[r] = cen;
        }
        // stash sy0 into w1p low halves later (needs cen1); hold in w1p temporarily
#pragma unroll
        for (int r = 0; r < 4; ++r) w1p[r] = __builtin_bit_cast(unsigned int, sy0[r]);
    }
    {   // channel c1 = 2cp+1
        const int c = 2 * cp + 1;
        float4v r0a = *(const float4v*)&u.sx[ty][c][tx4];
        float4v r0b = *(const float4v*)&u.sx[ty][c][tx4 + 4];
        float4v r1a = *(const float4v*)&u.sx[ty + 1][c][tx4];
        float4v r1b = *(const float4v*)&u.sx[ty + 1][c][tx4 + 4];
        float4v r2a = *(const float4v*)&u.sx[ty + 2][c][tx4];
        float4v r2b = *(const float4v*)&u.sx[ty + 2][c][tx4 + 4];
        float S[6], D[6];
#pragma unroll
        for (int j = 0; j < 6; ++j) {
            float a0 = (j < 4) ? r0a[j] : r0b[j - 4];
            float a1v = (j < 4) ? r1a[j] : r1b[j - 4];
            float a2 = (j < 4) ? r2a[j] : r2b[j - 4];
            S[j] = fmaf(2.f, a1v, a0) + a2;
            D[j] = a2 - a0;
        }
#pragma unroll
        for (int r = 0; r < 4; ++r) {
            float cen = (r + 1 < 4) ? r1a[r + 1] : r1b[r - 3];
            float sxv = (S[r + 2] - S[r]) * 0.125f;
            float syv = (fmaf(2.f, D[r + 1], D[r]) + D[r + 2]) * 0.125f;
            float sy0 = __builtin_bit_cast(float, w1p[r]);
            w1p[r] = pack2(sy0, cen);
            w2p[r] = pack2(sxv, syv);
            cen1v[r] = cen;
        }
        if (cp == 1) {
            // c==3: begin-alive maxpool3 (zero-pad == -inf pad since x >= 0)
            unsigned int bits = 0;
#pragma unroll
            for (int r = 0; r < 4; ++r) {
                float m0 = -1.f;
#pragma unroll
                for (int j = 0; j < 3; ++j) {
                    float a0 = (r + j < 4) ? r0a[r + j] : r0b[r + j - 4];
                    float a1v = (r + j < 4) ? r1a[r + j] : r1b[r + j - 4];
                    float a2 = (r + j < 4) ? r2a[r + j] : r2b[r + j - 4];
                    m0 = fmaxf(m0, fmaxf(a0, fmaxf(a1v, a2)));
                }
                bits |= (m0 > 0.1f ? 1u : 0u) << (8 * r);
            }
            *(unsigned int*)(bm + (size_t)b * HW + (i0 + ty) * IMW + j0 + tx4) = bits;
        }
    }
    // xcT (XOR-swizzled on float-index bits 2..4; float4-aligned blocks)
    *(float4v*)&xcT[2 * cp][(4 * qd) ^ (((2 * cp) & 7) << 2)] = cen0v;
    *(float4v*)&xcT[2 * cp + 1][(4 * qd) ^ (((2 * cp + 1) & 7) << 2)] = cen1v;
    // ybuf: one b128 per pixel: physical group cp at swizzled slot (cp^ykey(p)).
    // 4th word: slots 8cp+6,7 -> cp==0 carries {bias=1.0, 0}; others zero (weights 0).
    {
        const unsigned int u3 = (cp == 0) ? 0x3F80u : 0u;
#pragma unroll
        for (int r = 0; r < 4; ++r) {
            const int p = 4 * qd + r;
            uint4v g = {w0p[r], w1p[r], w2p[r], u3};
            *(uint4v*)&((unsigned int*)&ybuf[p][0])[(cp ^ ykey(p)) << 2] = g;
        }
    }
    __syncthreads();

    // ---- per wave: GEMM1-T -> h scratch -> GEMM2 -> epilogue ----
    float* ob = out + (size_t)b * CN * HW;
    float* n3 = xn3 + (size_t)b * HW;
#pragma unroll
    for (int half = 0; half < 2; ++half) {
        const int nt  = w + 4 * half;
        const int row = 16 * nt + l15;
        const unsigned short* yr = &ybuf[row][0];
        const int rsw = ykey(row);
        short8 y0 = *(const short8*)(yr + ((q ^ rsw) << 3));
        short8 y1 = *(const short8*)(yr + (((4 + q) ^ rsw) << 3));
        const int hsw = l15 & 7;
#pragma unroll
        for (int mi = 0; mi < 8; ++mi) {
            float4v acc = {};
            acc = __builtin_amdgcn_mfma_f32_16x16x32_bf16(a1[mi][0], y0, acc, 0, 0, 0);
            acc = __builtin_amdgcn_mfma_f32_16x16x32_bf16(a1[mi][1], y1, acc, 0, 0, 0);
            uint2v hp;
            hp[0] = pack2(fmaxf(acc[0], 0.f), fmaxf(acc[1], 0.f));
            hp[1] = pack2(fmaxf(acc[2], 0.f), fmaxf(acc[3], 0.f));
            // logical col 16mi+4q -> group 2mi+(q>>1), offset 4(q&1); XOR-swizzled
            *(uint2v*)&u.hb[w][l15][(((2 * mi + (q >> 1)) ^ hsw) << 3) + ((q & 1) << 2)] = hp;
        }
        float4v acc2 = {};
#pragma unroll
        for (int ks = 0; ks < 4; ++ks) {
            short8 hf = *(const short8*)&u.hb[w][l15][((4 * ks + q) ^ hsw) << 3];
            acc2 = __builtin_amdgcn_mfma_f32_16x16x32_bf16(hf, b2[ks], acc2, 0, 0, 0);
        }
        // epilogue: pixel p2 = 16nt+4q+r, channel = l15; 4 consecutive pixels -> dwordx4
        const int i  = i0 + (nt >> 1);
        const int jb = j0 + ((nt & 1) << 4) + (q << 2);
        float4v xc4 = *(const float4v*)&xcT[l15][(16 * nt + 4 * q) ^ ((l15 & 7) << 2)];
        float4v u4  = *(const float4v*)(ub + i * IMW + jb);
        float4v o;
#pragma unroll
        for (int r = 0; r < 4; ++r)
            o[r] = fmaf(acc2[r], (u4[r] <= 0.5f) ? 1.f : 0.f, xc4[r]);
        *(float4v*)(ob + l15 * HW + i * IMW + jb) = o;
        if (l15 == 3) *(float4v*)(n3 + i * IMW + jb) = o;
    }
}

// ---------------- Pass 2: alive masking ----------------
// alive = bm & (maxpool3(xn3) > 0.1); zero dead pixels (own pixel only).
// Full-row tiles (8x256), float4-staged.
__global__ __launch_bounds__(256) void nca_pass2(
    const float* __restrict__ xn3, const unsigned char* __restrict__ bm,
    float* __restrict__ out)
{
    __shared__ float s[10][264];           // data at col idx 4..259; halos at 3 and 260
    const int b   = blockIdx.z;
    const int i0  = blockIdx.y * 8;
    const int tid = threadIdx.x;
    const float* n3 = xn3 + (size_t)b * HW;

#pragma unroll
    for (int t = 0; t < 3; ++t) {
        const int idx = tid + 256 * t;     // 640 float4 slots: 10 rows x 64
        if (idx < 640) {
            const int r = idx >> 6, c4 = idx & 63;
            const int gi = i0 + r - 1;
            float4v vv;
            if ((unsigned)gi < IMH) vv = *(const float4v*)(n3 + gi * IMW + 4 * c4);
            else { vv[0] = vv[1] = vv[2] = vv[3] = -1e30f; }
            *(float4v*)&s[r][4 + 4 * c4] = vv;
        }
    }
    if (tid < 20) { const int r = tid >> 1; s[r][(tid & 1) ? 260 : 3] = -1e30f; }
    __syncthreads();

    const int c = tid;                     // column 0..255
    const unsigned char* bmb = bm + (size_t)b * HW + i0 * IMW + c;
    float* ob = out + (size_t)b * CN * HW;
#pragma unroll
    for (int r = 0; r < 8; ++r) {
        float m = fmaxf(fmaxf(fmaxf(s[r][c + 3], s[r][c + 4]), fmaxf(s[r][c + 5], s[r + 1][c + 3])),
                        fmaxf(fmaxf(s[r + 1][c + 4], s[r + 1][c + 5]),
                              fmaxf(fmaxf(s[r + 2][c + 3], s[r + 2][c + 4]), s[r + 2][c + 5])));
        if (!((m > 0.1f) && bmb[r * IMW])) {
            const int i = i0 + r;
#pragma unroll
            for (int ch = 0; ch < CN; ++ch)
                ob[ch * HW + i * IMW + c] = 0.f;
        }
    }
}

extern "C" void kernel_launch(void* const* d_in, const int* in_sizes, int n_in,
                              void* d_out, int out_size, void* d_ws, size_t ws_size,
                              hipStream_t stream) {
    const float* x   = (const float*)d_in[0];
    const float* upd = (const float*)d_in[1];
    const float* w1  = (const float*)d_in[2];
    const float* b1  = (const float*)d_in[3];
    const float* w2  = (const float*)d_in[4];
    float* out = (float*)d_out;

    char* ws = (char*)d_ws;
    float* xn3          = (float*)ws;                            // 8 MiB
    unsigned char* bmp  = (unsigned char*)(ws + (8u << 20));     // 2 MiB
    unsigned short* a1f = (unsigned short*)(ws + (10u << 20));   // 16 KiB
    unsigned short* b2f = a1f + 8192;                            // 4 KiB

    nca_prep<<<32, 256, 0, stream>>>(w1, b1, w2, a1f, b2f);
    nca_mfma<<<dim3(8, 64, 32), 256, 0, stream>>>(x, upd, a1f, b2f, out, xn3, bmp);
    nca_pass2<<<dim3(1, 32, 32), 256, 0, stream>>>(xn3, bmp, out);
}

// Round 11
// 409.058 us; speedup vs baseline: 1.0159x; 1.0159x over previous
//
#include <hip/hip_runtime.h>

#define CN 16
#define HN 128
#define IMH 256
#define IMW 256
#define HW (IMH * IMW)

typedef __attribute__((ext_vector_type(8))) short short8;
typedef __attribute__((ext_vector_type(4))) float float4v;
typedef __attribute__((ext_vector_type(2))) unsigned int uint2v;
typedef __attribute__((ext_vector_type(4))) unsigned int uint4v;

__device__ __forceinline__ unsigned int f2bf(float f) {
    unsigned int u = __builtin_bit_cast(unsigned int, f);
    u += 0x7FFFu + ((u >> 16) & 1u);          // round-to-nearest-even
    return u >> 16;
}
// HW packed f32->bf16 (RNE, identical rounding to f2bf)
__device__ __forceinline__ unsigned int pack2(float a, float b) {
    unsigned int r;
    asm("v_cvt_pk_bf16_f32 %0, %1, %2" : "=v"(r) : "v"(a), "v"(b));
    return r;
}

// ---------------- Weight prep: fragment-ordered bf16 weights (R1 layout) ----------------
// a1f[((mi*2+ks)*64+lane)*8+j] = bf16(w1[16mi+(lane&15)][32ks+8(lane>>4)+j]),
//   k==48 slot = b1[hid] (bias folded via y[48]=1.0), k>48 -> 0.
// b2f[(ks*64+lane)*8+j]        = bf16(w2[lane&15][32ks+8(lane>>4)+j])
__global__ void nca_prep(const float* __restrict__ w1, const float* __restrict__ b1,
                         const float* __restrict__ w2,
                         unsigned short* __restrict__ a1f, unsigned short* __restrict__ b2f)
{
    int t = blockIdx.x * 256 + threadIdx.x;
    if (t < 8192) {
        int j = t & 7, lane = (t >> 3) & 63, ks = (t >> 9) & 1, mi = t >> 10;
        int hid = 16 * mi + (lane & 15);
        int k = 32 * ks + 8 * (lane >> 4) + j;
        float v = 0.f;
        if (k < 48) v = w1[hid * 48 + k];
        else if (k == 48) v = b1[hid];
        a1f[t] = (unsigned short)f2bf(v);
    }
    if (t < 2048) {
        int j = t & 7, lane = (t >> 3) & 63, ks = t >> 9;
        b2f[t] = (unsigned short)f2bf(w2[(lane & 15) * HN + 32 * ks + 8 * (lane >> 4) + j]);
    }
}

// ---------------- Kernel A: perception + MFMA MLP + update ----------------
// R10 (resubmit; prior bench was an infra failure): ZERO barriers. Each of the 4
// waves is fully autonomous: it stages its own image row (+halo) into a private
// 10240 B LDS arena, perceives its own 32 pixels, packs its own y slice, and runs
// its own GEMM. Phase-reuse inside the arena (sx -> yb/xc/hb) is per-wave
// program-order safe (same-wave DS ops are in-order). Rationale: R1..R9 pinned at
// 243us with NOTHING saturated (VALU 29%, MFMA 7%, HBM 21%) — the 3 barriers
// lock-stepped all waves into the same stalls. 16 independent wave-streams/CU
// replace 4 lock-stepped blocks.
// Session rules kept: grid 8x64x32 (L2 blocking, R3); launch_bounds(256,4) only
// (R4); no extra VGPR state across perception (R5); LDS 4x10240 = 40960 exactly.
__global__ __launch_bounds__(256, 4) void nca_mfma(
    const float* __restrict__ x, const float* __restrict__ upd,
    const unsigned short* __restrict__ a1f, const unsigned short* __restrict__ b2f,
    float* __restrict__ out, float* __restrict__ xn3, unsigned char* __restrict__ bm)
{
    union Arena {
        float sx[3][16][34];                   // 6528 B (staging; dead after perception)
        struct {
            unsigned short yb[32][64];         // 4096 B (y, swizzled; rows = wave pixels)
            float          xc[16][32];         // 2048 B (x centers, parity-swizzled)
            unsigned short hb[16][128];        // 4096 B (h scratch, swizzled)
        } g;                                   // 10240 B
    };
    __shared__ __align__(16) Arena ar[4];      // 40960 B exactly -> 4 blocks/CU

    const int b   = blockIdx.z;
    const int i0  = blockIdx.y * 4;
    const int j0  = blockIdx.x * 32;
    const int tid = threadIdx.x;
    const int lane = tid & 63, w = tid >> 6;
    const int l15 = lane & 15, q = lane >> 4;
    Arena& A = ar[w];
    const int i1 = i0 + w;                     // this wave's image row
    const float* xb = x + (size_t)b * CN * HW;
    const float* ub = upd + (size_t)b * HW;

    // ---- weight fragment loads (L1/L2-hot; compiler sinks to use site — R1-proven) ----
    short8 a1[8][2];
#pragma unroll
    for (int mi = 0; mi < 8; ++mi)
#pragma unroll
        for (int ks = 0; ks < 2; ++ks)
            a1[mi][ks] = *(const short8*)(a1f + ((mi * 2 + ks) * 64 + lane) * 8);
    short8 b2[4];
#pragma unroll
    for (int ks = 0; ks < 4; ++ks)
        b2[ks] = *(const short8*)(b2f + (ks * 64 + lane) * 8);

    // ---- per-wave staging: rows i1-1..i1+1, 16 ch, cols j0-1..j0+32 (34) ----
    // main: 48 (row,ch) pairs x cols 0..31; lane -> (rc = (lane>>5)+2k, col = lane&31)
    // extras: 96 elems (cols 32,33) via e = lane, lane+64.
    const bool interior = (i1 > 0) & (i1 < 255) & (blockIdx.x > 0) & (blockIdx.x < 7);
    if (interior) {
        const float* src = xb + (i1 - 1) * IMW + (j0 - 1);
#pragma unroll
        for (int k = 0; k < 24; ++k) {
            const int rc = (lane >> 5) + 2 * k;
            A.sx[rc >> 4][rc & 15][lane & 31] = src[(rc & 15) * HW + (rc >> 4) * IMW + (lane & 31)];
        }
#pragma unroll
        for (int e = lane; e < 96; e += 64) {
            const int rc = e >> 1, col = 32 + (e & 1);
            A.sx[rc >> 4][rc & 15][col] = src[(rc & 15) * HW + (rc >> 4) * IMW + col];
        }
    } else {
#pragma unroll
        for (int k = 0; k < 24; ++k) {
            const int rc = (lane >> 5) + 2 * k;
            const int rr = rc >> 4, c = rc & 15;
            const int gi = i1 - 1 + rr, gj = j0 - 1 + (lane & 31);
            float vv = 0.f;
            if ((unsigned)gi < IMH && (unsigned)gj < IMW) vv = xb[c * HW + gi * IMW + gj];
            A.sx[rr][c][lane & 31] = vv;
        }
#pragma unroll
        for (int e = lane; e < 96; e += 64) {
            const int rc = e >> 1, col = 32 + (e & 1);
            const int rr = rc >> 4, c = rc & 15;
            const int gi = i1 - 1 + rr, gj = j0 - 1 + col;
            float vv = 0.f;
            if ((unsigned)gi < IMH && (unsigned)gj < IMW) vv = xb[c * HW + gi * IMW + gj];
            A.sx[rr][c][col] = vv;
        }
    }
    // no barrier: same-wave LDS RAW is ordered by the compiler's lgkmcnt waits

    // ---- perception: lane = (pixel txp, 8-channel half cb) of THIS wave's row ----
    const int txp = lane & 31;
    const int cb  = (lane >> 5) << 3;          // 0 or 8
    float v[24];
#pragma unroll
    for (int c8 = 0; c8 < 8; ++c8) {
        const int c = cb + c8;
        float a00 = A.sx[0][c][txp], a01 = A.sx[0][c][txp + 1], a02 = A.sx[0][c][txp + 2];
        float a10 = A.sx[1][c][txp], a11 = A.sx[1][c][txp + 1], a12 = A.sx[1][c][txp + 2];
        float a20 = A.sx[2][c][txp], a21 = A.sx[2][c][txp + 1], a22 = A.sx[2][c][txp + 2];
        v[3 * c8]     = a11;
        v[3 * c8 + 1] = ((a02 - a00) + 2.f * (a12 - a10) + (a22 - a20)) * 0.125f;
        v[3 * c8 + 2] = ((a20 - a00) + 2.f * (a21 - a01) + (a22 - a02)) * 0.125f;
        if (cb == 0 && c8 == 3) {
            // begin-alive: maxpool3 of x ch3 (zero-pad == -inf pad since x >= 0)
            float m0 = fmaxf(fmaxf(fmaxf(a00, a01), fmaxf(a02, a10)),
                             fmaxf(fmaxf(a11, a12), fmaxf(fmaxf(a20, a21), a22)));
            bm[(size_t)b * HW + i1 * IMW + (j0 + txp)] = (m0 > 0.1f) ? 1 : 0;
        }
    }
    // ---- phase switch: sx dead; write y / xc into the arena (program-order safe) ----
    {
        unsigned int* yrow = (unsigned int*)&A.g.yb[txp][0];
        const int gbase = (cb >> 3) * 3;
        const int sw = txp & 7;
#pragma unroll
        for (int t = 0; t < 3; ++t) {
            uint4v g;
#pragma unroll
            for (int k = 0; k < 4; ++k) g[k] = pack2(v[8 * t + 2 * k], v[8 * t + 2 * k + 1]);
            *(uint4v*)&yrow[((gbase + t) ^ sw) << 2] = g;
        }
        if (cb == 8) {
            uint4v g6 = {0x3F80u, 0u, 0u, 0u};   // y[48] = 1.0 (bias column)
            uint4v g7 = {};
            *(uint4v*)&yrow[(6 ^ sw) << 2] = g6;
            *(uint4v*)&yrow[(7 ^ sw) << 2] = g7;
        }
        // x centers (v[3*c8]), parity-swizzled so the float4 epilogue read is bank-spread
#pragma unroll
        for (int c8 = 0; c8 < 8; ++c8) {
            const int c = cb + c8;
            A.g.xc[c][txp ^ ((c & 1) << 4)] = v[3 * c8];
        }
    }
    // no barrier: GEMM reads this wave's own yb/xc

    // ---- per-wave GEMM1-T -> h scratch -> GEMM2 -> epilogue ----
    float* ob = out + (size_t)b * CN * HW;
    float* n3 = xn3 + (size_t)b * HW;
#pragma unroll
    for (int half = 0; half < 2; ++half) {
        const int prow = 16 * half + l15;        // wave-local pixel row of ybuf
        const unsigned short* yr = &A.g.yb[prow][0];
        const int rsw = prow & 7;
        short8 y0 = *(const short8*)(yr + ((q ^ rsw) << 3));
        short8 y1 = *(const short8*)(yr + (((4 + q) ^ rsw) << 3));
        const int hsw = l15 & 7;
#pragma unroll
        for (int mi = 0; mi < 8; ++mi) {
            float4v acc = {};
            acc = __builtin_amdgcn_mfma_f32_16x16x32_bf16(a1[mi][0], y0, acc, 0, 0, 0);
            acc = __builtin_amdgcn_mfma_f32_16x16x32_bf16(a1[mi][1], y1, acc, 0, 0, 0);
            uint2v hp;
            hp[0] = pack2(fmaxf(acc[0], 0.f), fmaxf(acc[1], 0.f));
            hp[1] = pack2(fmaxf(acc[2], 0.f), fmaxf(acc[3], 0.f));
            // logical col 16mi+4q -> group 2mi+(q>>1), offset 4(q&1); XOR-swizzled
            *(uint2v*)&A.g.hb[l15][(((2 * mi + (q >> 1)) ^ hsw) << 3) + ((q & 1) << 2)] = hp;
        }
        float4v acc2 = {};
#pragma unroll
        for (int ks = 0; ks < 4; ++ks) {
            short8 hf = *(const short8*)&A.g.hb[l15][((4 * ks + q) ^ hsw) << 3];
            acc2 = __builtin_amdgcn_mfma_f32_16x16x32_bf16(hf, b2[ks], acc2, 0, 0, 0);
        }
        // epilogue: wave-local pixel 16half+4q+r, channel l15 -> row i1, 4-col dwordx4
        const int jb = j0 + 16 * half + (q << 2);
        float4v xc4 = *(const float4v*)&A.g.xc[l15][(16 * half + 4 * q) ^ ((l15 & 1) << 4)];
        float4v u4  = *(const float4v*)(ub + i1 * IMW + jb);
        float4v o;
#pragma unroll
        for (int r = 0; r < 4; ++r)
            o[r] = fmaf(acc2[r], (u4[r] <= 0.5f) ? 1.f : 0.f, xc4[r]);
        *(float4v*)(ob + l15 * HW + i1 * IMW + jb) = o;
        if (l15 == 3) *(float4v*)(n3 + i1 * IMW + jb) = o;
    }
}

// ---------------- Pass 2: alive masking ----------------
// alive = bm & (maxpool3(xn3) > 0.1); zero dead pixels (own pixel only).
__global__ __launch_bounds__(256) void nca_pass2(
    const float* __restrict__ xn3, const unsigned char* __restrict__ bm,
    float* __restrict__ out)
{
    __shared__ float s[10][264];           // data at col idx 4..259; halos at 3 and 260
    const int b   = blockIdx.z;
    const int i0  = blockIdx.y * 8;
    const int tid = threadIdx.x;
    const float* n3 = xn3 + (size_t)b * HW;

#pragma unroll
    for (int t = 0; t < 3; ++t) {
        const int idx = tid + 256 * t;     // 640 float4 slots: 10 rows x 64
        if (idx < 640) {
            const int r = idx >> 6, c4 = idx & 63;
            const int gi = i0 + r - 1;
            float4v vv;
            if ((unsigned)gi < IMH) vv = *(const float4v*)(n3 + gi * IMW + 4 * c4);
            else { vv[0] = vv[1] = vv[2] = vv[3] = -1e30f; }
            *(float4v*)&s[r][4 + 4 * c4] = vv;
        }
    }
    if (tid < 20) { const int r = tid >> 1; s[r][(tid & 1) ? 260 : 3] = -1e30f; }
    __syncthreads();

    const int c = tid;                     // column 0..255
    const unsigned char* bmb = bm + (size_t)b * HW + i0 * IMW + c;
    float* ob = out + (size_t)b * CN * HW;
#pragma unroll
    for (int r = 0; r < 8; ++r) {
        float m = fmaxf(fmaxf(fmaxf(s[r][c + 3], s[r][c + 4]), fmaxf(s[r][c + 5], s[r + 1][c + 3])),
                        fmaxf(fmaxf(s[r + 1][c + 4], s[r + 1][c + 5]),
                              fmaxf(fmaxf(s[r + 2][c + 3], s[r + 2][c + 4]), s[r + 2][c + 5])));
        if (!((m > 0.1f) && bmb[r * IMW])) {
            const int i = i0 + r;
#pragma unroll
            for (int ch = 0; ch < CN; ++ch)
                ob[ch * HW + i * IMW + c] = 0.f;
        }
    }
}

extern "C" void kernel_launch(void* const* d_in, const int* in_sizes, int n_in,
                              void* d_out, int out_size, void* d_ws, size_t ws_size,
                              hipStream_t stream) {
    const float* x   = (const float*)d_in[0];
    const float* upd = (const float*)d_in[1];
    const float* w1  = (const float*)d_in[2];
    const float* b1  = (const float*)d_in[3];
    const float* w2  = (const float*)d_in[4];
    float* out = (float*)d_out;

    char* ws = (char*)d_ws;
    float* xn3          = (float*)ws;                            // 8 MiB
    unsigned char* bmp  = (unsigned char*)(ws + (8u << 20));     // 2 MiB
    unsigned short* a1f = (unsigned short*)(ws + (10u << 20));   // 16 KiB
    unsigned short* b2f = a1f + 8192;                            // 4 KiB

    nca_prep<<<32, 256, 0, stream>>>(w1, b1, w2, a1f, b2f);
    nca_mfma<<<dim3(8, 64, 32), 256, 0, stream>>>(x, upd, a1f, b2f, out, xn3, bmp);
    nca_pass2<<<dim3(1, 32, 32), 256, 0, stream>>>(xn3, bmp, out);
}

// Round 12
// 405.288 us; speedup vs baseline: 1.0253x; 1.0093x over previous
//
#include <hip/hip_runtime.h>

#define CN 16
#define HN 128
#define IMH 256
#define IMW 256
#define HW (IMH * IMW)

typedef __attribute__((ext_vector_type(8))) short short8;
typedef __attribute__((ext_vector_type(4))) float float4v;
typedef __attribute__((ext_vector_type(2))) unsigned int uint2v;
typedef __attribute__((ext_vector_type(4))) unsigned int uint4v;

__device__ __forceinline__ unsigned int f2bf(float f) {
    unsigned int u = __builtin_bit_cast(unsigned int, f);
    u += 0x7FFFu + ((u >> 16) & 1u);          // round-to-nearest-even
    return u >> 16;
}
// HW packed f32->bf16 (RNE, identical rounding to f2bf)
__device__ __forceinline__ unsigned int pack2(float a, float b) {
    unsigned int r;
    asm("v_cvt_pk_bf16_f32 %0, %1, %2" : "=v"(r) : "v"(a), "v"(b));
    return r;
}

// ---------------- Weight prep: fragment-ordered bf16 weights (R1 layout) ----------------
__global__ void nca_prep(const float* __restrict__ w1, const float* __restrict__ b1,
                         const float* __restrict__ w2,
                         unsigned short* __restrict__ a1f, unsigned short* __restrict__ b2f)
{
    int t = blockIdx.x * 256 + threadIdx.x;
    if (t < 8192) {
        int j = t & 7, lane = (t >> 3) & 63, ks = (t >> 9) & 1, mi = t >> 10;
        int hid = 16 * mi + (lane & 15);
        int k = 32 * ks + 8 * (lane >> 4) + j;
        float v = 0.f;
        if (k < 48) v = w1[hid * 48 + k];
        else if (k == 48) v = b1[hid];
        a1f[t] = (unsigned short)f2bf(v);
    }
    if (t < 2048) {
        int j = t & 7, lane = (t >> 3) & 63, ks = t >> 9;
        b2f[t] = (unsigned short)f2bf(w2[(lane & 15) * HN + 32 * ks + 8 * (lane >> 4) + j]);
    }
}

// ---------------- Kernel A: perception + MFMA MLP + update ----------------
// R12 = R11 zero-barrier wave-autonomous structure (232us, best) +
//  (a) global_load_lds staging for interior waves: 8x dwordx4 async -> LDS replaces
//      ~26 scalar VMEM + ~26 ds_write + addressing VALU (Common-mistake #1 fix);
//  (b) paired epilogue stores: hold half0's o, issue both 64B halves of each 128B
//      line back-to-back (R11 per-wave rows broke L2 sector merge: WRITE 207->281MB).
// sx layout: [48 rc][40 cols] floats, rc = rr*16+ch, col t = global j0-4+t.
// Chunk g = 10*rc + c4 at LDS byte 16g -> 8 instructions x 1024B contiguous.
// Pad chunks (g>=480, bytes 7680..8191) land in g.hb region: overwritten later. Safe.
// Session rules: grid 8x64x32 (L2 blocking, R3); launch_bounds(256,4) (R4);
// nothing extra lives across perception (R5); occupancy is LDS-story-capped (R6).
__global__ __launch_bounds__(256, 4) void nca_mfma(
    const float* __restrict__ x, const float* __restrict__ upd,
    const unsigned short* __restrict__ a1f, const unsigned short* __restrict__ b2f,
    float* __restrict__ out, float* __restrict__ xn3, unsigned char* __restrict__ bm)
{
    struct ArenaG {
        unsigned short yb[32][64];         // 4096 B (y, swizzled)
        float          xc[16][32];         // 2048 B (x centers, parity-swizzled)
        unsigned short hb[16][128];        // 4096 B (h scratch, swizzled)
    };
    union Arena {
        float sxf[48][40];                 // 7680 B staging (+512B pad spills into hb)
        ArenaG g;
        unsigned char raw[10240];
    };
    __shared__ __align__(16) Arena ar[4];  // 40960 B exactly -> 4 blocks/CU

    const int b   = blockIdx.z;
    const int i0  = blockIdx.y * 4;
    const int j0  = blockIdx.x * 32;
    const int tid = threadIdx.x;
    const int lane = tid & 63, w = tid >> 6;
    const int l15 = lane & 15, q = lane >> 4;
    Arena& A = ar[w];
    const int i1 = i0 + w;                 // this wave's image row
    const float* xb = x + (size_t)b * CN * HW;
    const float* ub = upd + (size_t)b * HW;

    // ---- weight fragment loads (L1/L2-hot) ----
    short8 a1[8][2];
#pragma unroll
    for (int mi = 0; mi < 8; ++mi)
#pragma unroll
        for (int ks = 0; ks < 2; ++ks)
            a1[mi][ks] = *(const short8*)(a1f + ((mi * 2 + ks) * 64 + lane) * 8);
    short8 b2[4];
#pragma unroll
    for (int ks = 0; ks < 4; ++ks)
        b2[ks] = *(const short8*)(b2f + (ks * 64 + lane) * 8);

    // ---- per-wave staging: rows i1-1..i1+1, 16 ch ----
    const bool interior = (i1 > 0) & (i1 < 255) & (blockIdx.x > 0) & (blockIdx.x < 7);
    if (interior) {
        // async global->LDS: 8 x dwordx4; lds dest contiguous 1024B per inst
        const float* gbase0 = xb + (size_t)(i1 - 1) * IMW + (j0 - 4);
#pragma unroll
        for (int k = 0; k < 8; ++k) {
            unsigned int g  = 64u * k + (unsigned)lane;
            unsigned int rc = g / 10u;
            unsigned int c4 = g - 10u * rc;
            rc = (rc < 48u) ? rc : 47u;    // pad lanes: clamp to a valid row (garbage ok)
            const float* gp = gbase0 + (rc & 15u) * HW + (rc >> 4) * IMW + 4u * c4;
            __builtin_amdgcn_global_load_lds(
                (const __attribute__((address_space(1))) unsigned int*)gp,
                (__attribute__((address_space(3))) unsigned int*)(unsigned int*)(A.raw + 1024 * k),
                16, 0, 0);
        }
        asm volatile("s_waitcnt vmcnt(0)" ::: "memory");
        __builtin_amdgcn_sched_barrier(0);
    } else {
        // boundary: scalar bounds-checked into cols 3..36 (global j0-1..j0+32)
#pragma unroll
        for (int k = 0; k < 24; ++k) {
            const int rc = (lane >> 5) + 2 * k;
            const int rr = rc >> 4, c = rc & 15;
            const int gi = i1 - 1 + rr, gj = j0 - 1 + (lane & 31);
            float vv = 0.f;
            if ((unsigned)gi < IMH && (unsigned)gj < IMW) vv = xb[c * HW + gi * IMW + gj];
            A.sxf[rc][3 + (lane & 31)] = vv;
        }
#pragma unroll
        for (int e = lane; e < 96; e += 64) {
            const int rc = e >> 1, col = 35 + (e & 1);     // global j0+31, j0+32
            const int rr = rc >> 4, c = rc & 15;
            const int gi = i1 - 1 + rr, gj = j0 - 4 + col;
            float vv = 0.f;
            if ((unsigned)gi < IMH && (unsigned)gj < IMW) vv = xb[c * HW + gi * IMW + gj];
            A.sxf[rc][col] = vv;
        }
    }
    // no barrier: same-wave LDS ordering (lgkmcnt / explicit vmcnt above)

    // ---- perception: lane = (pixel txp, 8-channel half cb) of THIS wave's row ----
    const int txp = lane & 31;
    const int cb  = (lane >> 5) << 3;          // 0 or 8
    float v[24];
#pragma unroll
    for (int c8 = 0; c8 < 8; ++c8) {
        const int c = cb + c8;
        float a00 = A.sxf[c][txp + 3],      a01 = A.sxf[c][txp + 4],      a02 = A.sxf[c][txp + 5];
        float a10 = A.sxf[16 + c][txp + 3], a11 = A.sxf[16 + c][txp + 4], a12 = A.sxf[16 + c][txp + 5];
        float a20 = A.sxf[32 + c][txp + 3], a21 = A.sxf[32 + c][txp + 4], a22 = A.sxf[32 + c][txp + 5];
        v[3 * c8]     = a11;
        v[3 * c8 + 1] = ((a02 - a00) + 2.f * (a12 - a10) + (a22 - a20)) * 0.125f;
        v[3 * c8 + 2] = ((a20 - a00) + 2.f * (a21 - a01) + (a22 - a02)) * 0.125f;
        if (cb == 0 && c8 == 3) {
            // begin-alive: maxpool3 of x ch3 (zero-pad == -inf pad since x >= 0)
            float m0 = fmaxf(fmaxf(fmaxf(a00, a01), fmaxf(a02, a10)),
                             fmaxf(fmaxf(a11, a12), fmaxf(fmaxf(a20, a21), a22)));
            bm[(size_t)b * HW + i1 * IMW + (j0 + txp)] = (m0 > 0.1f) ? 1 : 0;
        }
    }
    // ---- phase switch: sx dead; write y / xc into the arena (program-order safe) ----
    {
        unsigned int* yrow = (unsigned int*)&A.g.yb[txp][0];
        const int gbase = (cb >> 3) * 3;
        const int sw = txp & 7;
#pragma unroll
        for (int t = 0; t < 3; ++t) {
            uint4v g;
#pragma unroll
            for (int k = 0; k < 4; ++k) g[k] = pack2(v[8 * t + 2 * k], v[8 * t + 2 * k + 1]);
            *(uint4v*)&yrow[((gbase + t) ^ sw) << 2] = g;
        }
        if (cb == 8) {
            uint4v g6 = {0x3F80u, 0u, 0u, 0u};   // y[48] = 1.0 (bias column)
            uint4v g7 = {};
            *(uint4v*)&yrow[(6 ^ sw) << 2] = g6;
            *(uint4v*)&yrow[(7 ^ sw) << 2] = g7;
        }
        // x centers, parity-swizzled for the float4 epilogue read
#pragma unroll
        for (int c8 = 0; c8 < 8; ++c8) {
            const int c = cb + c8;
            A.g.xc[c][txp ^ ((c & 1) << 4)] = v[3 * c8];
        }
    }
    // no barrier: GEMM reads this wave's own yb/xc

    // ---- per-wave GEMM1-T -> h scratch -> GEMM2 -> paired epilogue ----
    float* ob = out + (size_t)b * CN * HW;
    float* n3 = xn3 + (size_t)b * HW;
    float4v osave = {};
#pragma unroll
    for (int half = 0; half < 2; ++half) {
        const int prow = 16 * half + l15;        // wave-local pixel row of ybuf
        const unsigned short* yr = &A.g.yb[prow][0];
        const int rsw = prow & 7;
        short8 y0 = *(const short8*)(yr + ((q ^ rsw) << 3));
        short8 y1 = *(const short8*)(yr + (((4 + q) ^ rsw) << 3));
        const int hsw = l15 & 7;
#pragma unroll
        for (int mi = 0; mi < 8; ++mi) {
            float4v acc = {};
            acc = __builtin_amdgcn_mfma_f32_16x16x32_bf16(a1[mi][0], y0, acc, 0, 0, 0);
            acc = __builtin_amdgcn_mfma_f32_16x16x32_bf16(a1[mi][1], y1, acc, 0, 0, 0);
            uint2v hp;
            hp[0] = pack2(fmaxf(acc[0], 0.f), fmaxf(acc[1], 0.f));
            hp[1] = pack2(fmaxf(acc[2], 0.f), fmaxf(acc[3], 0.f));
            // logical col 16mi+4q -> group 2mi+(q>>1), offset 4(q&1); XOR-swizzled
            *(uint2v*)&A.g.hb[l15][(((2 * mi + (q >> 1)) ^ hsw) << 3) + ((q & 1) << 2)] = hp;
        }
        float4v acc2 = {};
#pragma unroll
        for (int ks = 0; ks < 4; ++ks) {
            short8 hf = *(const short8*)&A.g.hb[l15][((4 * ks + q) ^ hsw) << 3];
            acc2 = __builtin_amdgcn_mfma_f32_16x16x32_bf16(hf, b2[ks], acc2, 0, 0, 0);
        }
        // epilogue: wave-local pixel 16half+4q+r, channel l15, row i1
        const int jb = j0 + 16 * half + (q << 2);
        float4v xc4 = *(const float4v*)&A.g.xc[l15][(16 * half + 4 * q) ^ ((l15 & 1) << 4)];
        float4v u4  = *(const float4v*)(ub + i1 * IMW + jb);
        float4v o;
#pragma unroll
        for (int r = 0; r < 4; ++r)
            o[r] = fmaf(acc2[r], (u4[r] <= 0.5f) ? 1.f : 0.f, xc4[r]);
        if (half == 0) {
            osave = o;                           // defer: pair the two 64B halves
        } else {
            float* orow = ob + (size_t)l15 * HW + i1 * IMW + j0;
            *(float4v*)(orow + (q << 2))      = osave;
            *(float4v*)(orow + 16 + (q << 2)) = o;
            if (l15 == 3) {
                float* nrow = n3 + i1 * IMW + j0;
                *(float4v*)(nrow + (q << 2))      = osave;
                *(float4v*)(nrow + 16 + (q << 2)) = o;
            }
        }
    }
}

// ---------------- Pass 2: alive masking ----------------
// alive = bm & (maxpool3(xn3) > 0.1); zero dead pixels (own pixel only).
__global__ __launch_bounds__(256) void nca_pass2(
    const float* __restrict__ xn3, const unsigned char* __restrict__ bm,
    float* __restrict__ out)
{
    __shared__ float s[10][264];           // data at col idx 4..259; halos at 3 and 260
    const int b   = blockIdx.z;
    const int i0  = blockIdx.y * 8;
    const int tid = threadIdx.x;
    const float* n3 = xn3 + (size_t)b * HW;

#pragma unroll
    for (int t = 0; t < 3; ++t) {
        const int idx = tid + 256 * t;     // 640 float4 slots: 10 rows x 64
        if (idx < 640) {
            const int r = idx >> 6, c4 = idx & 63;
            const int gi = i0 + r - 1;
            float4v vv;
            if ((unsigned)gi < IMH) vv = *(const float4v*)(n3 + gi * IMW + 4 * c4);
            else { vv[0] = vv[1] = vv[2] = vv[3] = -1e30f; }
            *(float4v*)&s[r][4 + 4 * c4] = vv;
        }
    }
    if (tid < 20) { const int r = tid >> 1; s[r][(tid & 1) ? 260 : 3] = -1e30f; }
    __syncthreads();

    const int c = tid;                     // column 0..255
    const unsigned char* bmb = bm + (size_t)b * HW + i0 * IMW + c;
    float* ob = out + (size_t)b * CN * HW;
#pragma unroll
    for (int r = 0; r < 8; ++r) {
        float m = fmaxf(fmaxf(fmaxf(s[r][c + 3], s[r][c + 4]), fmaxf(s[r][c + 5], s[r + 1][c + 3])),
                        fmaxf(fmaxf(s[r + 1][c + 4], s[r + 1][c + 5]),
                              fmaxf(fmaxf(s[r + 2][c + 3], s[r + 2][c + 4]), s[r + 2][c + 5])));
        if (!((m > 0.1f) && bmb[r * IMW])) {
            const int i = i0 + r;
#pragma unroll
            for (int ch = 0; ch < CN; ++ch)
                ob[ch * HW + i * IMW + c] = 0.f;
        }
    }
}

extern "C" void kernel_launch(void* const* d_in, const int* in_sizes, int n_in,
                              void* d_out, int out_size, void* d_ws, size_t ws_size,
                              hipStream_t stream) {
    const float* x   = (const float*)d_in[0];
    const float* upd = (const float*)d_in[1];
    const float* w1  = (const float*)d_in[2];
    const float* b1  = (const float*)d_in[3];
    const float* w2  = (const float*)d_in[4];
    float* out = (float*)d_out;

    char* ws = (char*)d_ws;
    float* xn3          = (float*)ws;                            // 8 MiB
    unsigned char* bmp  = (unsigned char*)(ws + (8u << 20));     // 2 MiB
    unsigned short* a1f = (unsigned short*)(ws + (10u << 20));   // 16 KiB
    unsigned short* b2f = a1f + 8192;                            // 4 KiB

    nca_prep<<<32, 256, 0, stream>>>(w1, b1, w2, a1f, b2f);
    nca_mfma<<<dim3(8, 64, 32), 256, 0, stream>>>(x, upd, a1f, b2f, out, xn3, bmp);
    nca_pass2<<<dim3(1, 32, 32), 256, 0, stream>>>(xn3, bmp, out);
}

// Round 13
// 399.754 us; speedup vs baseline: 1.0395x; 1.0138x over previous
//
#include <hip/hip_runtime.h>

#define CN 16
#define HN 128
#define IMH 256
#define IMW 256
#define HW (IMH * IMW)

typedef __attribute__((ext_vector_type(8))) short short8;
typedef __attribute__((ext_vector_type(4))) float float4v;
typedef __attribute__((ext_vector_type(2))) unsigned int uint2v;
typedef __attribute__((ext_vector_type(4))) unsigned int uint4v;

__device__ __forceinline__ unsigned int f2bf(float f) {
    unsigned int u = __builtin_bit_cast(unsigned int, f);
    u += 0x7FFFu + ((u >> 16) & 1u);          // round-to-nearest-even
    return u >> 16;
}
// HW packed f32->bf16 (RNE, identical rounding to f2bf)
__device__ __forceinline__ unsigned int pack2(float a, float b) {
    unsigned int r;
    asm("v_cvt_pk_bf16_f32 %0, %1, %2" : "=v"(r) : "v"(a), "v"(b));
    return r;
}

// ---------------- Weight prep: fragment-ordered bf16 weights (R1 layout) ----------------
__global__ void nca_prep(const float* __restrict__ w1, const float* __restrict__ b1,
                         const float* __restrict__ w2,
                         unsigned short* __restrict__ a1f, unsigned short* __restrict__ b2f)
{
    int t = blockIdx.x * 256 + threadIdx.x;
    if (t < 8192) {
        int j = t & 7, lane = (t >> 3) & 63, ks = (t >> 9) & 1, mi = t >> 10;
        int hid = 16 * mi + (lane & 15);
        int k = 32 * ks + 8 * (lane >> 4) + j;
        float v = 0.f;
        if (k < 48) v = w1[hid * 48 + k];
        else if (k == 48) v = b1[hid];
        a1f[t] = (unsigned short)f2bf(v);
    }
    if (t < 2048) {
        int j = t & 7, lane = (t >> 3) & 63, ks = t >> 9;
        b2f[t] = (unsigned short)f2bf(w2[(lane & 15) * HN + 32 * ks + 8 * (lane >> 4) + j]);
    }
}

// ---------------- Kernel A: perception + MFMA MLP + update ----------------
// R13 = R11 zero-barrier wave-autonomous structure (232us best) with:
//  (a) staging loads issued textually FIRST (HBM latency starts before the L2-hot
//      weight loads; compiler keeps counted per-use waits — R12 showed explicit
//      vmcnt(0)+global_load_lds drains the weight loads too and regresses);
//  (b) per-half upd preload at the TOP of each GEMM half: ~600-900cy of MFMA+LDS
//      work hides the L3/HBM latency that previously stalled the wave pre-store;
//      liveness stays within one half (+4 VGPR peak; avoids the R5 spill trap);
//  (c) R12's paired epilogue stores kept (WRITE 281->272, free).
// Session rules: grid 8x64x32 (L2 blocking, R3); launch_bounds(256,4) (R4);
// nothing extra lives across perception (R5); occupancy not wave-slot-limited (R6);
// bank conflicts are overlapped, not critical-path (R8/R9).
__global__ __launch_bounds__(256, 4) void nca_mfma(
    const float* __restrict__ x, const float* __restrict__ upd,
    const unsigned short* __restrict__ a1f, const unsigned short* __restrict__ b2f,
    float* __restrict__ out, float* __restrict__ xn3, unsigned char* __restrict__ bm)
{
    union Arena {
        float sx[3][16][34];                   // 6528 B (staging; dead after perception)
        struct {
            unsigned short yb[32][64];         // 4096 B (y, swizzled; rows = wave pixels)
            float          xc[16][32];         // 2048 B (x centers, parity-swizzled)
            unsigned short hb[16][128];        // 4096 B (h scratch, swizzled)
        } g;                                   // 10240 B
    };
    __shared__ __align__(16) Arena ar[4];      // 40960 B exactly -> 4 blocks/CU

    const int b   = blockIdx.z;
    const int i0  = blockIdx.y * 4;
    const int j0  = blockIdx.x * 32;
    const int tid = threadIdx.x;
    const int lane = tid & 63, w = tid >> 6;
    const int l15 = lane & 15, q = lane >> 4;
    Arena& A = ar[w];
    const int i1 = i0 + w;                     // this wave's image row
    const float* xb = x + (size_t)b * CN * HW;
    const float* ub = upd + (size_t)b * HW;

    // ---- per-wave staging FIRST: rows i1-1..i1+1, 16 ch, cols j0-1..j0+32 (34) ----
    const bool interior = (i1 > 0) & (i1 < 255) & (blockIdx.x > 0) & (blockIdx.x < 7);
    if (interior) {
        const float* src = xb + (i1 - 1) * IMW + (j0 - 1);
#pragma unroll
        for (int k = 0; k < 24; ++k) {
            const int rc = (lane >> 5) + 2 * k;
            A.sx[rc >> 4][rc & 15][lane & 31] = src[(rc & 15) * HW + (rc >> 4) * IMW + (lane & 31)];
        }
#pragma unroll
        for (int e = lane; e < 96; e += 64) {
            const int rc = e >> 1, col = 32 + (e & 1);
            A.sx[rc >> 4][rc & 15][col] = src[(rc & 15) * HW + (rc >> 4) * IMW + col];
        }
    } else {
#pragma unroll
        for (int k = 0; k < 24; ++k) {
            const int rc = (lane >> 5) + 2 * k;
            const int rr = rc >> 4, c = rc & 15;
            const int gi = i1 - 1 + rr, gj = j0 - 1 + (lane & 31);
            float vv = 0.f;
            if ((unsigned)gi < IMH && (unsigned)gj < IMW) vv = xb[c * HW + gi * IMW + gj];
            A.sx[rr][c][lane & 31] = vv;
        }
#pragma unroll
        for (int e = lane; e < 96; e += 64) {
            const int rc = e >> 1, col = 32 + (e & 1);
            const int rr = rc >> 4, c = rc & 15;
            const int gi = i1 - 1 + rr, gj = j0 - 1 + col;
            float vv = 0.f;
            if ((unsigned)gi < IMH && (unsigned)gj < IMW) vv = xb[c * HW + gi * IMW + gj];
            A.sx[rr][c][col] = vv;
        }
    }

    // ---- weight fragment loads (L1/L2-hot; compiler sinks waits to GEMM use) ----
    short8 a1[8][2];
#pragma unroll
    for (int mi = 0; mi < 8; ++mi)
#pragma unroll
        for (int ks = 0; ks < 2; ++ks)
            a1[mi][ks] = *(const short8*)(a1f + ((mi * 2 + ks) * 64 + lane) * 8);
    short8 b2[4];
#pragma unroll
    for (int ks = 0; ks < 4; ++ks)
        b2[ks] = *(const short8*)(b2f + (ks * 64 + lane) * 8);

    // no barrier: same-wave LDS RAW ordered by compiler lgkmcnt waits

    // ---- perception: lane = (pixel txp, 8-channel half cb) of THIS wave's row ----
    const int txp = lane & 31;
    const int cb  = (lane >> 5) << 3;          // 0 or 8
    float v[24];
#pragma unroll
    for (int c8 = 0; c8 < 8; ++c8) {
        const int c = cb + c8;
        float a00 = A.sx[0][c][txp], a01 = A.sx[0][c][txp + 1], a02 = A.sx[0][c][txp + 2];
        float a10 = A.sx[1][c][txp], a11 = A.sx[1][c][txp + 1], a12 = A.sx[1][c][txp + 2];
        float a20 = A.sx[2][c][txp], a21 = A.sx[2][c][txp + 1], a22 = A.sx[2][c][txp + 2];
        v[3 * c8]     = a11;
        v[3 * c8 + 1] = ((a02 - a00) + 2.f * (a12 - a10) + (a22 - a20)) * 0.125f;
        v[3 * c8 + 2] = ((a20 - a00) + 2.f * (a21 - a01) + (a22 - a02)) * 0.125f;
        if (cb == 0 && c8 == 3) {
            // begin-alive: maxpool3 of x ch3 (zero-pad == -inf pad since x >= 0)
            float m0 = fmaxf(fmaxf(fmaxf(a00, a01), fmaxf(a02, a10)),
                             fmaxf(fmaxf(a11, a12), fmaxf(fmaxf(a20, a21), a22)));
            bm[(size_t)b * HW + i1 * IMW + (j0 + txp)] = (m0 > 0.1f) ? 1 : 0;
        }
    }
    // ---- phase switch: sx dead; write y / xc into the arena (program-order safe) ----
    {
        unsigned int* yrow = (unsigned int*)&A.g.yb[txp][0];
        const int gbase = (cb >> 3) * 3;
        const int sw = txp & 7;
#pragma unroll
        for (int t = 0; t < 3; ++t) {
            uint4v g;
#pragma unroll
            for (int k = 0; k < 4; ++k) g[k] = pack2(v[8 * t + 2 * k], v[8 * t + 2 * k + 1]);
            *(uint4v*)&yrow[((gbase + t) ^ sw) << 2] = g;
        }
        if (cb == 8) {
            uint4v g6 = {0x3F80u, 0u, 0u, 0u};   // y[48] = 1.0 (bias column)
            uint4v g7 = {};
            *(uint4v*)&yrow[(6 ^ sw) << 2] = g6;
            *(uint4v*)&yrow[(7 ^ sw) << 2] = g7;
        }
        // x centers (v[3*c8]), parity-swizzled so the float4 epilogue read is bank-spread
#pragma unroll
        for (int c8 = 0; c8 < 8; ++c8) {
            const int c = cb + c8;
            A.g.xc[c][txp ^ ((c & 1) << 4)] = v[3 * c8];
        }
    }
    // no barrier: GEMM reads this wave's own yb/xc

    // ---- per-wave GEMM1-T -> h scratch -> GEMM2 -> paired epilogue ----
    float* ob = out + (size_t)b * CN * HW;
    float* n3 = xn3 + (size_t)b * HW;
    float4v osave = {};
#pragma unroll
    for (int half = 0; half < 2; ++half) {
        // issue this half's upd load NOW: GEMM1+hb work below hides its latency
        const int jb = j0 + 16 * half + (q << 2);
        float4v u4 = *(const float4v*)(ub + i1 * IMW + jb);

        const int prow = 16 * half + l15;        // wave-local pixel row of ybuf
        const unsigned short* yr = &A.g.yb[prow][0];
        const int rsw = prow & 7;
        short8 y0 = *(const short8*)(yr + ((q ^ rsw) << 3));
        short8 y1 = *(const short8*)(yr + (((4 + q) ^ rsw) << 3));
        const int hsw = l15 & 7;
#pragma unroll
        for (int mi = 0; mi < 8; ++mi) {
            float4v acc = {};
            acc = __builtin_amdgcn_mfma_f32_16x16x32_bf16(a1[mi][0], y0, acc, 0, 0, 0);
            acc = __builtin_amdgcn_mfma_f32_16x16x32_bf16(a1[mi][1], y1, acc, 0, 0, 0);
            uint2v hp;
            hp[0] = pack2(fmaxf(acc[0], 0.f), fmaxf(acc[1], 0.f));
            hp[1] = pack2(fmaxf(acc[2], 0.f), fmaxf(acc[3], 0.f));
            // logical col 16mi+4q -> group 2mi+(q>>1), offset 4(q&1); XOR-swizzled
            *(uint2v*)&A.g.hb[l15][(((2 * mi + (q >> 1)) ^ hsw) << 3) + ((q & 1) << 2)] = hp;
        }
        float4v acc2 = {};
#pragma unroll
        for (int ks = 0; ks < 4; ++ks) {
            short8 hf = *(const short8*)&A.g.hb[l15][((4 * ks + q) ^ hsw) << 3];
            acc2 = __builtin_amdgcn_mfma_f32_16x16x32_bf16(hf, b2[ks], acc2, 0, 0, 0);
        }
        // epilogue: wave-local pixel 16half+4q+r, channel l15, row i1
        float4v xc4 = *(const float4v*)&A.g.xc[l15][(16 * half + 4 * q) ^ ((l15 & 1) << 4)];
        float4v o;
#pragma unroll
        for (int r = 0; r < 4; ++r)
            o[r] = fmaf(acc2[r], (u4[r] <= 0.5f) ? 1.f : 0.f, xc4[r]);
        if (half == 0) {
            osave = o;                           // defer: pair the two 64B halves
        } else {
            float* orow = ob + (size_t)l15 * HW + i1 * IMW + j0;
            *(float4v*)(orow + (q << 2))      = osave;
            *(float4v*)(orow + 16 + (q << 2)) = o;
            if (l15 == 3) {
                float* nrow = n3 + i1 * IMW + j0;
                *(float4v*)(nrow + (q << 2))      = osave;
                *(float4v*)(nrow + 16 + (q << 2)) = o;
            }
        }
    }
}

// ---------------- Pass 2: alive masking ----------------
// alive = bm & (maxpool3(xn3) > 0.1); zero dead pixels (own pixel only).
__global__ __launch_bounds__(256) void nca_pass2(
    const float* __restrict__ xn3, const unsigned char* __restrict__ bm,
    float* __restrict__ out)
{
    __shared__ float s[10][264];           // data at col idx 4..259; halos at 3 and 260
    const int b   = blockIdx.z;
    const int i0  = blockIdx.y * 8;
    const int tid = threadIdx.x;
    const float* n3 = xn3 + (size_t)b * HW;

#pragma unroll
    for (int t = 0; t < 3; ++t) {
        const int idx = tid + 256 * t;     // 640 float4 slots: 10 rows x 64
        if (idx < 640) {
            const int r = idx >> 6, c4 = idx & 63;
            const int gi = i0 + r - 1;
            float4v vv;
            if ((unsigned)gi < IMH) vv = *(const float4v*)(n3 + gi * IMW + 4 * c4);
            else { vv[0] = vv[1] = vv[2] = vv[3] = -1e30f; }
            *(float4v*)&s[r][4 + 4 * c4] = vv;
        }
    }
    if (tid < 20) { const int r = tid >> 1; s[r][(tid & 1) ? 260 : 3] = -1e30f; }
    __syncthreads();

    const int c = tid;                     // column 0..255
    const unsigned char* bmb = bm + (size_t)b * HW + i0 * IMW + c;
    float* ob = out + (size_t)b * CN * HW;
#pragma unroll
    for (int r = 0; r < 8; ++r) {
        float m = fmaxf(fmaxf(fmaxf(s[r][c + 3], s[r][c + 4]), fmaxf(s[r][c + 5], s[r + 1][c + 3])),
                        fmaxf(fmaxf(s[r + 1][c + 4], s[r + 1][c + 5]),
                              fmaxf(fmaxf(s[r + 2][c + 3], s[r + 2][c + 4]), s[r + 2][c + 5])));
        if (!((m > 0.1f) && bmb[r * IMW])) {
            const int i = i0 + r;
#pragma unroll
            for (int ch = 0; ch < CN; ++ch)
                ob[ch * HW + i * IMW + c] = 0.f;
        }
    }
}

extern "C" void kernel_launch(void* const* d_in, const int* in_sizes, int n_in,
                              void* d_out, int out_size, void* d_ws, size_t ws_size,
                              hipStream_t stream) {
    const float* x   = (const float*)d_in[0];
    const float* upd = (const float*)d_in[1];
    const float* w1  = (const float*)d_in[2];
    const float* b1  = (const float*)d_in[3];
    const float* w2  = (const float*)d_in[4];
    float* out = (float*)d_out;

    char* ws = (char*)d_ws;
    float* xn3          = (float*)ws;                            // 8 MiB
    unsigned char* bmp  = (unsigned char*)(ws + (8u << 20));     // 2 MiB
    unsigned short* a1f = (unsigned short*)(ws + (10u << 20));   // 16 KiB
    unsigned short* b2f = a1f + 8192;                            // 4 KiB

    nca_prep<<<32, 256, 0, stream>>>(w1, b1, w2, a1f, b2f);
    nca_mfma<<<dim3(8, 64, 32), 256, 0, stream>>>(x, upd, a1f, b2f, out, xn3, bmp);
    nca_pass2<<<dim3(1, 32, 32), 256, 0, stream>>>(xn3, bmp, out);
}